// Round 1
// 360.340 us; speedup vs baseline: 1.0380x; 1.0380x over previous
//
#include <hip/hip_runtime.h>
#include <hip/hip_bf16.h>
#include <math.h>

// ---------------------------------------------------------------------------
// FeatureAttnNet v5 for MI355X (gfx950)
//
// score[b,f] = Y0[b,f] + sum_c cmd[b,c]*Yc[b,f], Y = X @ WKfold^T (BN folded,
// additive BN term cancels in softmax). V GEMM fused with softmax weights.
// v5 fused_attn: staging via global_load_lds dwordx4 (linear LDS dest +
// pre-swizzled global source, rule-21) — removes st[] regs + ds_writes that
// were spilling (WRITE_SIZE 126MB vs 16MB out). 1 barrier per V-tile, dbuf,
// setprio(1) around MFMA cluster.
// Gram: NO atomics — bf16 partials in d_out (scratch before final write).
// ---------------------------------------------------------------------------

typedef float  f32x4   __attribute__((ext_vector_type(4)));
typedef float  f32x16  __attribute__((ext_vector_type(16)));
typedef __bf16 bf16x4  __attribute__((ext_vector_type(4)));
typedef __bf16 bf16x8  __attribute__((ext_vector_type(8)));

#define MFMA16(A, B, C) __builtin_amdgcn_mfma_f32_16x16x32_bf16((A), (B), (C), 0, 0, 0)
#define MFMA32(A, B, C) __builtin_amdgcn_mfma_f32_32x32x16_bf16((A), (B), (C), 0, 0, 0)

#define EPSV 1e-5f

// ---- workspace layout (bytes) ----
#define WS_WV    0x000000u   // 2048*256 bf16 = 1 MiB  [Wvz;Wvh]
#define WS_WKF   0x100000u   // 2*96*256 bf16 = 96 KiB folded K weights (zero-padded)
#define WS_G     0x120000u   // 2*256*256 f32 = 512 KiB
#define WS_CS    0x1A0000u   // 2*256 f32 colsums (zeroed)
#define WS_CMDP  0x1A0800u   // 32*14 f32 cmd partials
#define WS_T     0x1A1800u   // 2048 f32
#define WS_U     0x1A3800u   // 2048 f32
#define WS_WQ2   0x1A5800u   // 256 f32
#define WS_C0    0x1A5C00u   // 64 f32

// async global->LDS, 16B per lane; LDS dest is wave-uniform base + lane*16.
__device__ __forceinline__ void gl_lds16(const void* g, void* l)
{
    __builtin_amdgcn_global_load_lds(
        (const __attribute__((address_space(1))) unsigned int*)g,
        (__attribute__((address_space(3))) unsigned int*)l, 16, 0, 0);
}

// ---------------------------------------------------------------------------
// setup1: blk<128 -> gram partials (bf16 -> d_out); 128..383 -> prepV;
// 384..415 -> cmd stats.
__global__ __launch_bounds__(512, 2) void setup1(const float* __restrict__ feat,
        const float* __restrict__ hid, const float4* __restrict__ cmd,
        const float* __restrict__ Wvz, const float* __restrict__ Wvh,
        __bf16* __restrict__ WV, float* __restrict__ CMDP, float* __restrict__ CS,
        __bf16* __restrict__ Gp)
{
    __shared__ __bf16 T[256 * 40];
    __shared__ float sm[8][14];
    const int blk = blockIdx.x;
    const int tid = threadIdx.x;

    if (blk >= 384) {                     // ---- cmd stats: 32 blocks ----
        const int b2 = blk - 384;
        float v[14];
#pragma unroll
        for (int k = 0; k < 14; ++k) v[k] = 0.f;
#pragma unroll
        for (int i = 0; i < 4; ++i) {
            float4 c = cmd[(b2 * 4 + i) * 512 + tid];
            v[0] += c.x;  v[1] += c.y;  v[2] += c.z;  v[3] += c.w;
            v[4] += c.x*c.x; v[5] += c.x*c.y; v[6] += c.x*c.z; v[7] += c.x*c.w;
            v[8] += c.y*c.y; v[9] += c.y*c.z; v[10] += c.y*c.w;
            v[11] += c.z*c.z; v[12] += c.z*c.w; v[13] += c.w*c.w;
        }
#pragma unroll
        for (int k = 0; k < 14; ++k) {
            float s = v[k];
#pragma unroll
            for (int off = 32; off; off >>= 1) s += __shfl_xor(s, off);
            if ((tid & 63) == 0) sm[tid >> 6][k] = s;
        }
        __syncthreads();
        if (tid < 14) {
            float s = 0.f;
#pragma unroll
            for (int w = 0; w < 8; ++w) s += sm[w][tid];
            CMDP[b2 * 14 + tid] = s;
        }
        return;
    }
    if (blk >= 128) {                     // ---- prepV: 256 blocks ----
        int t = (blk - 128) * 512 + tid;
        int e = t * 4;
        const float* src = (e < 262144) ? (Wvz + e) : (Wvh + (e - 262144));
        float4 a = *(const float4*)src;
        bf16x4 vv = { (__bf16)a.x, (__bf16)a.y, (__bf16)a.z, (__bf16)a.w };
        *(bf16x4*)(WV + e) = vv;
        return;
    }

    // ---- gram: 128 blocks = 2 mats x 64 chunks x 1024 rows ----
    const int mat  = blk >> 6;
    const int chunk = blk & 63;
    const float* X = mat ? hid : feat;
    float* cs = CS + mat * 256;
    const int k0   = chunk * 1024;
    const int wid  = tid >> 6, lane = tid & 63, quad = lane >> 4, l15 = lane & 15;
    const int c    = tid & 255;
    const int t8   = tid >> 8;

    f32x4 acc[2][16];
#pragma unroll
    for (int mt = 0; mt < 2; ++mt)
#pragma unroll
        for (int nt = 0; nt < 16; ++nt) acc[mt][nt] = (f32x4){0.f, 0.f, 0.f, 0.f};

    float clsum = 0.f;
    for (int it = 0; it < 32; ++it) {
        __syncthreads();
        const int kb = k0 + it * 32;
#pragma unroll
        for (int i = 0; i < 16; ++i) {
            int k = t8 + 2 * i;
            float x = X[(size_t)(kb + k) * 256 + c];
            clsum += x;
            T[c * 40 + k] = (__bf16)x;
        }
        __syncthreads();
        bf16x8 a0 = *(const bf16x8*)&T[(wid * 32 +      l15) * 40 + quad * 8];
        bf16x8 a1 = *(const bf16x8*)&T[(wid * 32 + 16 + l15) * 40 + quad * 8];
#pragma unroll
        for (int nt = 0; nt < 16; ++nt) {
            bf16x8 b = *(const bf16x8*)&T[(nt * 16 + l15) * 40 + quad * 8];
            acc[0][nt] = MFMA16(a0, b, acc[0][nt]);
            acc[1][nt] = MFMA16(a1, b, acc[1][nt]);
        }
    }
    atomicAdd(&cs[c], clsum);             // 512 addrs, 128-way — cheap
    __bf16* outp = Gp + (size_t)blk * 65536;
#pragma unroll
    for (int mt = 0; mt < 2; ++mt)
#pragma unroll
        for (int nt = 0; nt < 16; ++nt)
#pragma unroll
            for (int r = 0; r < 4; ++r) {
                int gi = wid * 32 + mt * 16 + quad * 4 + r;
                int gj = nt * 16 + l15;
                outp[gi * 256 + gj] = (__bf16)acc[mt][nt][r];
            }
}

// ---------------------------------------------------------------------------
__global__ void gram_reduce(const __bf16* __restrict__ Gp, float* __restrict__ G)
{
    int o = blockIdx.x * 256 + threadIdx.x;      // 512 x 256 = 131072
    int mat = o >> 16, e = o & 65535;
    const __bf16* p = Gp + (size_t)mat * 64 * 65536 + e;
    float s = 0.f;
#pragma unroll 8
    for (int c = 0; c < 64; ++c) s += (float)p[(size_t)c * 65536];
    G[o] = s;
}

// ---------------------------------------------------------------------------
__global__ void rowstats(const float* __restrict__ Wkz, const float* __restrict__ Wkh,
        const float* __restrict__ G, const float* __restrict__ CS,
        float* __restrict__ Tout, float* __restrict__ Uout)
{
    const int blk = blockIdx.x;               // 256 blocks
    const int mat = blk >> 7, jg = blk & 127;
    const float* Wsrc = (mat ? Wkh : Wkz) + (size_t)jg * 8 * 256;
    const float* Gm = G + (size_t)mat * 65536;
    const float* cs = CS + mat * 256;
    __shared__ float wlT[256 * 8];
    __shared__ float red[4][16];
    const int tid = threadIdx.x, wid = tid >> 6, lane = tid & 63;
#pragma unroll
    for (int jj = 0; jj < 8; ++jj) wlT[tid * 8 + jj] = Wsrc[jj * 256 + tid];
    __syncthreads();
    float inner[8];
#pragma unroll
    for (int jj = 0; jj < 8; ++jj) inner[jj] = 0.f;
    for (int r = 0; r < 256; ++r) {
        float g = Gm[r * 256 + tid];
        float4 w0 = *(const float4*)&wlT[r * 8];
        float4 w1 = *(const float4*)&wlT[r * 8 + 4];
        inner[0] = fmaf(w0.x, g, inner[0]); inner[1] = fmaf(w0.y, g, inner[1]);
        inner[2] = fmaf(w0.z, g, inner[2]); inner[3] = fmaf(w0.w, g, inner[3]);
        inner[4] = fmaf(w1.x, g, inner[4]); inner[5] = fmaf(w1.y, g, inner[5]);
        inner[6] = fmaf(w1.z, g, inner[6]); inner[7] = fmaf(w1.w, g, inner[7]);
    }
    float cst = cs[tid];
#pragma unroll
    for (int jj = 0; jj < 8; ++jj) {
        float wme = wlT[tid * 8 + jj];
        float p = wme * inner[jj];
        float u = wme * cst;
#pragma unroll
        for (int off = 32; off; off >>= 1) { p += __shfl_xor(p, off); u += __shfl_xor(u, off); }
        if (lane == 0) { red[wid][jj] = p; red[wid][jj + 8] = u; }
    }
    __syncthreads();
    if (tid < 16) {
        float s = red[0][tid] + red[1][tid] + red[2][tid] + red[3][tid];
        int jj = tid & 7;
        int j = mat * 1024 + jg * 8 + jj;
        if (tid < 8) Tout[j] = s; else Uout[j] = s;
    }
}

// ---------------------------------------------------------------------------
__global__ void finalize_kernel(const float* __restrict__ Wq,
        const float* __restrict__ gQ, const float* __restrict__ bQ,
        const float* __restrict__ gK, const float* __restrict__ bK,
        const float* __restrict__ CMDP, const float* __restrict__ T,
        const float* __restrict__ U, float* __restrict__ Wq2, float* __restrict__ C0)
{
    __shared__ float s14[14];
    const int d = threadIdx.x;
    if (d < 14) {
        float s = 0.f;
        for (int b = 0; b < 32; ++b) s += CMDP[b * 14 + d];
        s14[d] = s;
    }
    __syncthreads();
    float s4[4] = { s14[0], s14[1], s14[2], s14[3] };
    float gc[4][4];
    gc[0][0] = s14[4];
    gc[0][1] = gc[1][0] = s14[5];
    gc[0][2] = gc[2][0] = s14[6];
    gc[0][3] = gc[3][0] = s14[7];
    gc[1][1] = s14[8];
    gc[1][2] = gc[2][1] = s14[9];
    gc[1][3] = gc[3][1] = s14[10];
    gc[2][2] = s14[11];
    gc[2][3] = gc[3][2] = s14[12];
    gc[3][3] = s14[13];
    float wq[4];
#pragma unroll
    for (int c = 0; c < 4; ++c) wq[c] = Wq[d * 4 + c];
    const float invB = 1.0f / 65536.0f;
    float mQ = (wq[0]*s4[0] + wq[1]*s4[1] + wq[2]*s4[2] + wq[3]*s4[3]) * invB;
    float eq2 = 0.f;
#pragma unroll
    for (int c = 0; c < 4; ++c)
#pragma unroll
        for (int c2 = 0; c2 < 4; ++c2) eq2 += wq[c] * wq[c2] * gc[c][c2];
    eq2 *= invB;
    float vQ  = eq2 - mQ * mQ;
    float aQ  = gQ[d] / sqrtf(vQ + EPSV);
    float bQv = bQ[d] - mQ * aQ;
    float S2 = 0.f, S1 = 0.f;
#pragma unroll
    for (int f = 0; f < 32; ++f) { S2 += T[f * 64 + d]; S1 += U[f * 64 + d]; }
    const float invBF = 1.0f / (65536.0f * 32.0f);
    float e2 = S2 * invBF, mK = S1 * invBF;
    float vK = e2 - mK * mK;
    float aK = gK[d] / sqrtf(vK + EPSV);
    float c1 = aQ * aK * 0.125f;      // 1/sqrt(64) folded in
    C0[d] = bQv * aK * 0.125f;
#pragma unroll
    for (int c = 0; c < 4; ++c) Wq2[d * 4 + c] = c1 * wq[c];
}

// ---------------------------------------------------------------------------
// WKF[h][r = c*16 + fl][k] = sum_d coef_c[d]*W_h[fl*64+d][k]; rows 80..95 = 0.
__global__ void foldK(const float* __restrict__ Wkz, const float* __restrict__ Wkh,
                      const float* __restrict__ Wq2, const float* __restrict__ C0,
                      __bf16* __restrict__ WKF)
{
    const int blk = blockIdx.x;               // 192
    const int h = blk / 96, rr = blk % 96;
    const int k = threadIdx.x;
    float s = 0.f;
    if (rr < 80) {
        const int c = rr >> 4, fl = rr & 15;
        const float* Wsrc = (h ? Wkh : Wkz) + (size_t)fl * 64 * 256;
        for (int d = 0; d < 64; ++d) {
            float coef = (c == 0) ? C0[d] : Wq2[d * 4 + (c - 1)];
            s = fmaf(coef, Wsrc[d * 256 + k], s);
        }
    }
    WKF[(size_t)(h * 96 + rr) * 256 + k] = (__bf16)s;
}

// ---------------------------------------------------------------------------
// fused_attn v5: 512 blocks x 256 threads; wave = 32 rows; B staged via
// global_load_lds (linear LDS dest, pre-swizzled global src); dbuf V tiles,
// 1 barrier per tile; X read once; setprio(1) around MFMA cluster.
__global__ __launch_bounds__(256, 2) void fused_attn(
        const float* __restrict__ feat, const float* __restrict__ hid,
        const float4* __restrict__ cmd, const __bf16* __restrict__ WV,
        const __bf16* __restrict__ WKF, float* __restrict__ out)
{
    __shared__ __bf16 BUF[32768];             // 64 KiB (dbuf 2x32KB / p1 48KB)
    __shared__ __bf16 WGTs[16 * 128];         // 4 KiB, [f][row]
    const int tid  = threadIdx.x;
    const int wid  = tid >> 6, lane = tid & 63;
    const int l5   = lane & 31, hi = lane >> 5;
    const int fl   = l5 & 15;
    const bool low = (l5 < 16);
    const int wrow = (blockIdx.x << 7) + (wid << 5);   // wave's 32 rows

    // Staging chunk i (per wave): rows n = wid*2 + i*8 + (lane>>5), 64 lanes x
    // 16B = 1KiB linear LDS at elem (wid*2+i*8)*256. Source element offset is
    // pre-swizzled so BUF[n*256 + q*8+e] = SRC[n*256 + (q^(n&7))*8+e], i.e.
    // identical layout to the old xor-swizzled ds_write — reads unchanged.
    int voff[12];
#pragma unroll
    for (int i = 0; i < 12; ++i) {
        int n = (wid << 1) + (i << 3) + hi;
        voff[i] = n * 256 + ((l5 ^ (n & 7)) << 3);
    }

    float l_i[16];
    f32x16 s_acc[2];
#pragma unroll
    for (int r = 0; r < 16; ++r) { l_i[r] = 0.f; s_acc[0][r] = 0.f; s_acc[1][r] = 0.f; }

    for (int h = 0; h < 2; ++h) {
        const float* X = h ? hid : feat;
        const __bf16* Wkf = WKF + ((size_t)h * 96 << 8);

        // ---- A fragments (32x32x16): row wrow+l5, k = u*16 + hi*8 + j ----
        bf16x8 a2[16];
#pragma unroll
        for (int u = 0; u < 16; ++u) {
            const float* p = X + ((size_t)(wrow + l5) << 8) + u * 16 + hi * 8;
            float4 x0 = *(const float4*)p;
            float4 x1 = *(const float4*)(p + 4);
            a2[u] = (bf16x8){ (__bf16)x0.x, (__bf16)x0.y, (__bf16)x0.z, (__bf16)x0.w,
                              (__bf16)x1.x, (__bf16)x1.y, (__bf16)x1.z, (__bf16)x1.w };
        }

        // ---- phase 1: stage WKF (96 rows, 48KB) and compute scores ----
        __syncthreads();                      // prior readers of BUF done
#pragma unroll
        for (int i = 0; i < 12; ++i)
            gl_lds16(Wkf + voff[i], &BUF[((wid << 1) + (i << 3)) << 8]);
        __syncthreads();                      // barrier drain waits staging

        f32x16 acc1[3];
#pragma unroll
        for (int nt = 0; nt < 3; ++nt)
#pragma unroll
            for (int r = 0; r < 16; ++r) acc1[nt][r] = 0.f;
        __builtin_amdgcn_s_setprio(1);
#pragma unroll
        for (int ks = 0; ks < 16; ++ks)
#pragma unroll
            for (int nt = 0; nt < 3; ++nt) {
                int n = nt * 32 + l5;
                bf16x8 b = *(const bf16x8*)&BUF[n * 256 + (((ks * 2 + hi) ^ (n & 7)) << 3)];
                acc1[nt] = MFMA32(a2[ks], b, acc1[nt]);
            }
        __builtin_amdgcn_s_setprio(0);

        // epilogue: combine c-terms, exp, store wgt, accumulate l
#pragma unroll
        for (int g = 0; g < 4; ++g) {
            bf16x4 wv4;
#pragma unroll
            for (int j = 0; j < 4; ++j) {
                const int r = g * 4 + j;
                const int row32 = j + 8 * g + 4 * hi;
                float4 cm = cmd[wrow + row32];
                float e0, e1, t0[3], t1[3];
#pragma unroll
                for (int nt = 0; nt < 3; ++nt) {
                    e0 = acc1[nt][r];
                    e1 = __shfl_xor(e0, 16);
                    t0[nt] = low ? e0 : e1;
                    t1[nt] = low ? e1 : e0;
                }
                float sc = t0[0] + cm.x * t1[0] + cm.y * t0[1]
                                 + cm.z * t1[1] + cm.w * t0[2];
                float w = __expf(sc);
                wv4[j] = (__bf16)w;
                float ws = w;
                ws += __shfl_xor(ws, 1); ws += __shfl_xor(ws, 2);
                ws += __shfl_xor(ws, 4); ws += __shfl_xor(ws, 8);
                l_i[r] += ws;
            }
            if (low) *(bf16x4*)&WGTs[fl * 128 + (wid << 5) + 8 * g + 4 * hi] = wv4;
        }

        __syncthreads();                      // phase-1 BUF reads done

        // first V tile of this half -> buf0 (cold once per half; L2-resident)
        {
            const __bf16* base = WV + ((size_t)(h * 16) << 14);
#pragma unroll
            for (int i = 0; i < 8; ++i)
                gl_lds16(base + voff[i], &BUF[((wid << 1) + (i << 3)) << 8]);
        }

        // ---- phase 2: 16 V tiles, dbuf, 1 barrier each ----
        for (int f2 = 0; f2 < 16; ++f2) {
            const int bufsel = (f2 & 1) << 14;
            __syncthreads();                  // drains cur staging; ends prev reads
            if (f2 < 15) {                    // prefetch next tile into other buf
                const __bf16* base = WV + ((size_t)(h * 16 + f2 + 1) << 14);
                const int nsel = bufsel ^ 16384;
#pragma unroll
                for (int i = 0; i < 8; ++i)
                    gl_lds16(base + voff[i], &BUF[nsel + ((((wid << 1) + (i << 3))) << 8)]);
            }
            __builtin_amdgcn_sched_barrier(0);   // pin prefetch-issue before MFMAs
            f32x16 acc2[2];
#pragma unroll
            for (int r = 0; r < 16; ++r) { acc2[0][r] = 0.f; acc2[1][r] = 0.f; }
            __builtin_amdgcn_s_setprio(1);
#pragma unroll
            for (int ks = 0; ks < 16; ++ks)
#pragma unroll
                for (int nt = 0; nt < 2; ++nt) {
                    int n = nt * 32 + l5;
                    bf16x8 b = *(const bf16x8*)&BUF[bufsel + n * 256
                                                    + (((ks * 2 + hi) ^ (n & 7)) << 3)];
                    acc2[nt] = MFMA32(a2[ks], b, acc2[nt]);
                }
            __builtin_amdgcn_s_setprio(0);
#pragma unroll
            for (int g = 0; g < 4; ++g) {
                bf16x4 wv = *(const bf16x4*)&WGTs[f2 * 128 + (wid << 5) + 8 * g + 4 * hi];
#pragma unroll
                for (int j = 0; j < 4; ++j) {
                    float w = (float)wv[j];
                    s_acc[0][g * 4 + j] += w * acc2[0][g * 4 + j];
                    s_acc[1][g * 4 + j] += w * acc2[1][g * 4 + j];
                }
            }
        }
    }

    // ---- epilogue: divide by l, store ----
#pragma unroll
    for (int g = 0; g < 4; ++g)
#pragma unroll
        for (int j = 0; j < 4; ++j) {
            const int r = g * 4 + j;
            float inv = 1.0f / l_i[r];
            size_t row = (size_t)(wrow + j + 8 * g + 4 * hi);
            out[(row << 6) + l5]      = s_acc[0][r] * inv;
            out[(row << 6) + 32 + l5] = s_acc[1][r] * inv;
        }
}

// ---------------------------------------------------------------------------
extern "C" void kernel_launch(void* const* d_in, const int* in_sizes, int n_in,
                              void* d_out, int out_size, void* d_ws, size_t ws_size,
                              hipStream_t stream)
{
    (void)in_sizes; (void)n_in; (void)out_size; (void)ws_size;
    const float* feature = (const float*)d_in[0];
    const float* hidden  = (const float*)d_in[1];
    const float* command = (const float*)d_in[2];
    const float* Wq      = (const float*)d_in[3];
    const float* Wkz     = (const float*)d_in[4];
    const float* Wkh     = (const float*)d_in[5];
    const float* Wvz     = (const float*)d_in[6];
    const float* Wvh     = (const float*)d_in[7];
    const float* gammaQ  = (const float*)d_in[8];
    const float* betaQ   = (const float*)d_in[9];
    const float* gammaK  = (const float*)d_in[10];
    const float* betaK   = (const float*)d_in[11];

    char* ws = (char*)d_ws;
    __bf16* WV   = (__bf16*)(ws + WS_WV);
    __bf16* WKF  = (__bf16*)(ws + WS_WKF);
    float*  G    = (float*)(ws + WS_G);
    float*  CS   = (float*)(ws + WS_CS);
    float*  CMDP = (float*)(ws + WS_CMDP);
    float*  Tj   = (float*)(ws + WS_T);
    float*  Uj   = (float*)(ws + WS_U);
    float*  Wq2  = (float*)(ws + WS_WQ2);
    float*  C0   = (float*)(ws + WS_C0);
    float*  outp = (float*)d_out;
    __bf16* Gp   = (__bf16*)d_out;            // 16 MB scratch before final write

    hipMemsetAsync(ws + WS_CS, 0, 0x800, stream);
    setup1<<<416, 512, 0, stream>>>(feature, hidden, (const float4*)command,
                                    Wvz, Wvh, WV, CMDP, CS, Gp);
    gram_reduce<<<512, 256, 0, stream>>>(Gp, G);
    rowstats<<<256, 256, 0, stream>>>(Wkz, Wkh, G, CS, Tj, Uj);
    finalize_kernel<<<1, 64, 0, stream>>>(Wq, gammaQ, betaQ, gammaK, betaK,
                                          CMDP, Tj, Uj, Wq2, C0);
    foldK<<<192, 256, 0, stream>>>(Wkz, Wkh, Wq2, C0, WKF);
    fused_attn<<<512, 256, 0, stream>>>(feature, hidden, (const float4*)command,
                                        WV, WKF, outp);
}

// Round 2
// 336.970 us; speedup vs baseline: 1.1100x; 1.0694x over previous
//
#include <hip/hip_runtime.h>
#include <hip/hip_bf16.h>
#include <math.h>

// ---------------------------------------------------------------------------
// FeatureAttnNet v6 for MI355X (gfx950)
//
// score[b,f] = Y0[b,f] + sum_c cmd[b,c]*Yc[b,f], Y = X @ WKfold^T (BN folded,
// additive BN term cancels in softmax). V GEMM fused with softmax weights.
// v6: fused_attn: kill a2 register spills (WRITE_SIZE was 82MB vs 16MB out)
//   by capping transient register spikes: sched_barrier(0)-chunked a2 loads
//   (max 8 loads in flight) and per-g fences in the phase-1 epilogue; voff[]
//   array removed (recomputed inline). Staging stays global_load_lds w/
//   pre-swizzled source (rule-21).
// setup1 gram: dbuf LDS (2x20KB) + 2-deep register prefetch, 1 barrier/iter
//   (was 2 barriers + full vmcnt(0) HBM drain per iter with 1 block/CU).
// Gram: NO atomics — bf16 partials in d_out (scratch before final write).
// ---------------------------------------------------------------------------

typedef float  f32x4   __attribute__((ext_vector_type(4)));
typedef float  f32x16  __attribute__((ext_vector_type(16)));
typedef __bf16 bf16x4  __attribute__((ext_vector_type(4)));
typedef __bf16 bf16x8  __attribute__((ext_vector_type(8)));

#define MFMA16(A, B, C) __builtin_amdgcn_mfma_f32_16x16x32_bf16((A), (B), (C), 0, 0, 0)
#define MFMA32(A, B, C) __builtin_amdgcn_mfma_f32_32x32x16_bf16((A), (B), (C), 0, 0, 0)

#define EPSV 1e-5f

// ---- workspace layout (bytes) ----
#define WS_WV    0x000000u   // 2048*256 bf16 = 1 MiB  [Wvz;Wvh]
#define WS_WKF   0x100000u   // 2*96*256 bf16 = 96 KiB folded K weights (zero-padded)
#define WS_G     0x120000u   // 2*256*256 f32 = 512 KiB
#define WS_CS    0x1A0000u   // 2*256 f32 colsums (zeroed)
#define WS_CMDP  0x1A0800u   // 32*14 f32 cmd partials
#define WS_T     0x1A1800u   // 2048 f32
#define WS_U     0x1A3800u   // 2048 f32
#define WS_WQ2   0x1A5800u   // 256 f32
#define WS_C0    0x1A5C00u   // 64 f32

// async global->LDS, 16B per lane; LDS dest is wave-uniform base + lane*16.
__device__ __forceinline__ void gl_lds16(const void* g, void* l)
{
    __builtin_amdgcn_global_load_lds(
        (const __attribute__((address_space(1))) unsigned int*)g,
        (__attribute__((address_space(3))) unsigned int*)l, 16, 0, 0);
}

// ---------------------------------------------------------------------------
// setup1: blk<128 -> gram partials (bf16 -> d_out); 128..383 -> prepV;
// 384..415 -> cmd stats.
__global__ __launch_bounds__(512, 2) void setup1(const float* __restrict__ feat,
        const float* __restrict__ hid, const float4* __restrict__ cmd,
        const float* __restrict__ Wvz, const float* __restrict__ Wvh,
        __bf16* __restrict__ WV, float* __restrict__ CMDP, float* __restrict__ CS,
        __bf16* __restrict__ Gp)
{
    __shared__ __bf16 T[2 * 256 * 40];        // 40 KiB double buffer
    __shared__ float sm[8][14];
    const int blk = blockIdx.x;
    const int tid = threadIdx.x;

    if (blk >= 384) {                     // ---- cmd stats: 32 blocks ----
        const int b2 = blk - 384;
        float v[14];
#pragma unroll
        for (int k = 0; k < 14; ++k) v[k] = 0.f;
#pragma unroll
        for (int i = 0; i < 4; ++i) {
            float4 c = cmd[(b2 * 4 + i) * 512 + tid];
            v[0] += c.x;  v[1] += c.y;  v[2] += c.z;  v[3] += c.w;
            v[4] += c.x*c.x; v[5] += c.x*c.y; v[6] += c.x*c.z; v[7] += c.x*c.w;
            v[8] += c.y*c.y; v[9] += c.y*c.z; v[10] += c.y*c.w;
            v[11] += c.z*c.z; v[12] += c.z*c.w; v[13] += c.w*c.w;
        }
#pragma unroll
        for (int k = 0; k < 14; ++k) {
            float s = v[k];
#pragma unroll
            for (int off = 32; off; off >>= 1) s += __shfl_xor(s, off);
            if ((tid & 63) == 0) sm[tid >> 6][k] = s;
        }
        __syncthreads();
        if (tid < 14) {
            float s = 0.f;
#pragma unroll
            for (int w = 0; w < 8; ++w) s += sm[w][tid];
            CMDP[b2 * 14 + tid] = s;
        }
        return;
    }
    if (blk >= 128) {                     // ---- prepV: 256 blocks ----
        int t = (blk - 128) * 512 + tid;
        int e = t * 4;
        const float* src = (e < 262144) ? (Wvz + e) : (Wvh + (e - 262144));
        float4 a = *(const float4*)src;
        bf16x4 vv = { (__bf16)a.x, (__bf16)a.y, (__bf16)a.z, (__bf16)a.w };
        *(bf16x4*)(WV + e) = vv;
        return;
    }

    // ---- gram: 128 blocks = 2 mats x 64 chunks x 1024 rows ----
    // Pipelined: T dbuf, 2-deep reg prefetch, 1 barrier per 32-row step.
    const int mat  = blk >> 6;
    const int chunk = blk & 63;
    const float* X = mat ? hid : feat;
    float* cs = CS + mat * 256;
    const int k0   = chunk * 1024;
    const int wid  = tid >> 6, lane = tid & 63, quad = lane >> 4, l15 = lane & 15;
    const int c    = tid & 255;
    const int t8   = tid >> 8;

    f32x4 acc[2][16];
#pragma unroll
    for (int mt = 0; mt < 2; ++mt)
#pragma unroll
        for (int nt = 0; nt < 16; ++nt) acc[mt][nt] = (f32x4){0.f, 0.f, 0.f, 0.f};

    const float* Xc = X + (size_t)k0 * 256 + c;   // element (k, c) at Xc[k*256]
    float ra[16], rb[16];
    float clsum = 0.f;

#define GRAM_LOAD(R, IT) do { \
        const float* p_ = Xc + (size_t)(IT) * 32 * 256; \
        _Pragma("unroll") \
        for (int i_ = 0; i_ < 16; ++i_) (R)[i_] = p_[(size_t)(t8 + 2 * i_) * 256]; \
    } while (0)
#define GRAM_WRITE(R, BUFO) do { \
        _Pragma("unroll") \
        for (int i_ = 0; i_ < 16; ++i_) { \
            float x_ = (R)[i_]; clsum += x_; \
            T[(BUFO) + c * 40 + t8 + 2 * i_] = (__bf16)x_; } \
    } while (0)
#define GRAM_MFMA(BUFO) do { \
        const __bf16* Tb_ = &T[(BUFO)]; \
        bf16x8 a0_ = *(const bf16x8*)&Tb_[(wid * 32 +      l15) * 40 + quad * 8]; \
        bf16x8 a1_ = *(const bf16x8*)&Tb_[(wid * 32 + 16 + l15) * 40 + quad * 8]; \
        _Pragma("unroll") \
        for (int nt_ = 0; nt_ < 16; ++nt_) { \
            bf16x8 b_ = *(const bf16x8*)&Tb_[(nt_ * 16 + l15) * 40 + quad * 8]; \
            acc[0][nt_] = MFMA16(a0_, b_, acc[0][nt_]); \
            acc[1][nt_] = MFMA16(a1_, b_, acc[1][nt_]); } \
    } while (0)

    GRAM_LOAD(ra, 0);                     // it0
    GRAM_LOAD(rb, 1);                     // it1
    GRAM_WRITE(ra, 0);                    // it0 -> T0
    GRAM_LOAD(ra, 2);                     // it2 (consumed body B of it2=0)
    __syncthreads();

    for (int it2 = 0; it2 < 16; ++it2) {
        // body A: write rb (it 2*it2+1) -> T1; refill rb <- it 2*it2+3; MFMA T0
        GRAM_WRITE(rb, 10240);
        if (it2 < 15) GRAM_LOAD(rb, 2 * it2 + 3);
        GRAM_MFMA(0);
        __syncthreads();
        // body B: write ra (it 2*it2+2) -> T0; refill ra <- it 2*it2+4; MFMA T1
        if (it2 < 15) {
            GRAM_WRITE(ra, 0);
            if (it2 < 14) GRAM_LOAD(ra, 2 * it2 + 4);
        }
        GRAM_MFMA(10240);
        __syncthreads();
    }
#undef GRAM_LOAD
#undef GRAM_WRITE
#undef GRAM_MFMA

    atomicAdd(&cs[c], clsum);             // 512 addrs, 128-way — cheap
    __bf16* outp = Gp + (size_t)blk * 65536;
#pragma unroll
    for (int mt = 0; mt < 2; ++mt)
#pragma unroll
        for (int nt = 0; nt < 16; ++nt)
#pragma unroll
            for (int r = 0; r < 4; ++r) {
                int gi = wid * 32 + mt * 16 + quad * 4 + r;
                int gj = nt * 16 + l15;
                outp[gi * 256 + gj] = (__bf16)acc[mt][nt][r];
            }
}

// ---------------------------------------------------------------------------
__global__ void gram_reduce(const __bf16* __restrict__ Gp, float* __restrict__ G)
{
    int o = blockIdx.x * 256 + threadIdx.x;      // 512 x 256 = 131072
    int mat = o >> 16, e = o & 65535;
    const __bf16* p = Gp + (size_t)mat * 64 * 65536 + e;
    float s = 0.f;
#pragma unroll 8
    for (int c = 0; c < 64; ++c) s += (float)p[(size_t)c * 65536];
    G[o] = s;
}

// ---------------------------------------------------------------------------
__global__ void rowstats(const float* __restrict__ Wkz, const float* __restrict__ Wkh,
        const float* __restrict__ G, const float* __restrict__ CS,
        float* __restrict__ Tout, float* __restrict__ Uout)
{
    const int blk = blockIdx.x;               // 256 blocks
    const int mat = blk >> 7, jg = blk & 127;
    const float* Wsrc = (mat ? Wkh : Wkz) + (size_t)jg * 8 * 256;
    const float* Gm = G + (size_t)mat * 65536;
    const float* cs = CS + mat * 256;
    __shared__ float wlT[256 * 8];
    __shared__ float red[4][16];
    const int tid = threadIdx.x, wid = tid >> 6, lane = tid & 63;
#pragma unroll
    for (int jj = 0; jj < 8; ++jj) wlT[tid * 8 + jj] = Wsrc[jj * 256 + tid];
    __syncthreads();
    float inner[8];
#pragma unroll
    for (int jj = 0; jj < 8; ++jj) inner[jj] = 0.f;
    for (int r = 0; r < 256; ++r) {
        float g = Gm[r * 256 + tid];
        float4 w0 = *(const float4*)&wlT[r * 8];
        float4 w1 = *(const float4*)&wlT[r * 8 + 4];
        inner[0] = fmaf(w0.x, g, inner[0]); inner[1] = fmaf(w0.y, g, inner[1]);
        inner[2] = fmaf(w0.z, g, inner[2]); inner[3] = fmaf(w0.w, g, inner[3]);
        inner[4] = fmaf(w1.x, g, inner[4]); inner[5] = fmaf(w1.y, g, inner[5]);
        inner[6] = fmaf(w1.z, g, inner[6]); inner[7] = fmaf(w1.w, g, inner[7]);
    }
    float cst = cs[tid];
#pragma unroll
    for (int jj = 0; jj < 8; ++jj) {
        float wme = wlT[tid * 8 + jj];
        float p = wme * inner[jj];
        float u = wme * cst;
#pragma unroll
        for (int off = 32; off; off >>= 1) { p += __shfl_xor(p, off); u += __shfl_xor(u, off); }
        if (lane == 0) { red[wid][jj] = p; red[wid][jj + 8] = u; }
    }
    __syncthreads();
    if (tid < 16) {
        float s = red[0][tid] + red[1][tid] + red[2][tid] + red[3][tid];
        int jj = tid & 7;
        int j = mat * 1024 + jg * 8 + jj;
        if (tid < 8) Tout[j] = s; else Uout[j] = s;
    }
}

// ---------------------------------------------------------------------------
__global__ void finalize_kernel(const float* __restrict__ Wq,
        const float* __restrict__ gQ, const float* __restrict__ bQ,
        const float* __restrict__ gK, const float* __restrict__ bK,
        const float* __restrict__ CMDP, const float* __restrict__ T,
        const float* __restrict__ U, float* __restrict__ Wq2, float* __restrict__ C0)
{
    __shared__ float s14[14];
    const int d = threadIdx.x;
    if (d < 14) {
        float s = 0.f;
        for (int b = 0; b < 32; ++b) s += CMDP[b * 14 + d];
        s14[d] = s;
    }
    __syncthreads();
    float s4[4] = { s14[0], s14[1], s14[2], s14[3] };
    float gc[4][4];
    gc[0][0] = s14[4];
    gc[0][1] = gc[1][0] = s14[5];
    gc[0][2] = gc[2][0] = s14[6];
    gc[0][3] = gc[3][0] = s14[7];
    gc[1][1] = s14[8];
    gc[1][2] = gc[2][1] = s14[9];
    gc[1][3] = gc[3][1] = s14[10];
    gc[2][2] = s14[11];
    gc[2][3] = gc[3][2] = s14[12];
    gc[3][3] = s14[13];
    float wq[4];
#pragma unroll
    for (int c = 0; c < 4; ++c) wq[c] = Wq[d * 4 + c];
    const float invB = 1.0f / 65536.0f;
    float mQ = (wq[0]*s4[0] + wq[1]*s4[1] + wq[2]*s4[2] + wq[3]*s4[3]) * invB;
    float eq2 = 0.f;
#pragma unroll
    for (int c = 0; c < 4; ++c)
#pragma unroll
        for (int c2 = 0; c2 < 4; ++c2) eq2 += wq[c] * wq[c2] * gc[c][c2];
    eq2 *= invB;
    float vQ  = eq2 - mQ * mQ;
    float aQ  = gQ[d] / sqrtf(vQ + EPSV);
    float bQv = bQ[d] - mQ * aQ;
    float S2 = 0.f, S1 = 0.f;
#pragma unroll
    for (int f = 0; f < 32; ++f) { S2 += T[f * 64 + d]; S1 += U[f * 64 + d]; }
    const float invBF = 1.0f / (65536.0f * 32.0f);
    float e2 = S2 * invBF, mK = S1 * invBF;
    float vK = e2 - mK * mK;
    float aK = gK[d] / sqrtf(vK + EPSV);
    float c1 = aQ * aK * 0.125f;      // 1/sqrt(64) folded in
    C0[d] = bQv * aK * 0.125f;
#pragma unroll
    for (int c = 0; c < 4; ++c) Wq2[d * 4 + c] = c1 * wq[c];
}

// ---------------------------------------------------------------------------
// WKF[h][r = c*16 + fl][k] = sum_d coef_c[d]*W_h[fl*64+d][k]; rows 80..95 = 0.
__global__ void foldK(const float* __restrict__ Wkz, const float* __restrict__ Wkh,
                      const float* __restrict__ Wq2, const float* __restrict__ C0,
                      __bf16* __restrict__ WKF)
{
    const int blk = blockIdx.x;               // 192
    const int h = blk / 96, rr = blk % 96;
    const int k = threadIdx.x;
    float s = 0.f;
    if (rr < 80) {
        const int c = rr >> 4, fl = rr & 15;
        const float* Wsrc = (h ? Wkh : Wkz) + (size_t)fl * 64 * 256;
        for (int d = 0; d < 64; ++d) {
            float coef = (c == 0) ? C0[d] : Wq2[d * 4 + (c - 1)];
            s = fmaf(coef, Wsrc[d * 256 + k], s);
        }
    }
    WKF[(size_t)(h * 96 + rr) * 256 + k] = (__bf16)s;
}

// ---------------------------------------------------------------------------
// fused_attn v6: 512 blocks x 256 threads; wave = 32 rows; B staged via
// global_load_lds (linear LDS dest, pre-swizzled global src); dbuf V tiles,
// 1 barrier per tile; X read once; register-spike fences to prevent a2 spill.
__global__ __launch_bounds__(256, 2) void fused_attn(
        const float* __restrict__ feat, const float* __restrict__ hid,
        const float4* __restrict__ cmd, const __bf16* __restrict__ WV,
        const __bf16* __restrict__ WKF, float* __restrict__ out)
{
    __shared__ __bf16 BUF[32768];             // 64 KiB (dbuf 2x32KB / p1 48KB)
    __shared__ __bf16 WGTs[16 * 128];         // 4 KiB, [f][row]
    const int tid  = threadIdx.x;
    const int wid  = tid >> 6, lane = tid & 63;
    const int l5   = lane & 31, hi = lane >> 5;
    const int fl   = l5 & 15;
    const bool low = (l5 < 16);
    const int wrow = (blockIdx.x << 7) + (wid << 5);   // wave's 32 rows

    // Staging chunk i (per wave): rows n = wid*2 + i*8 + hi, 64 lanes x 16B =
    // 1KiB linear LDS at elem (wid*2+i*8)*256. Source element offset is
    // pre-swizzled so BUF[n*256 + q*8+e] = SRC[n*256 + (q^(n&7))*8+e] — same
    // layout as an xor-swizzled ds_write; reads unchanged. Offsets computed
    // inline (no live-across-kernel voff[] array).
#define STAGE_CHUNK(SRC, DSTBASE, I) do { \
        int n_ = (wid << 1) + ((I) << 3) + hi; \
        gl_lds16((SRC) + n_ * 256 + ((l5 ^ (n_ & 7)) << 3), \
                 &BUF[(DSTBASE) + (((wid << 1) + ((I) << 3)) << 8)]); \
    } while (0)

    float l_i[16];
    f32x16 s_acc[2];
#pragma unroll
    for (int r = 0; r < 16; ++r) { l_i[r] = 0.f; s_acc[0][r] = 0.f; s_acc[1][r] = 0.f; }

    for (int h = 0; h < 2; ++h) {
        const float* X = h ? hid : feat;
        const __bf16* Wkf = WKF + ((size_t)h * 96 << 8);

        // ---- A fragments (32x32x16): row wrow+l5, k = u*16 + hi*8 + j ----
        // sched_barrier every 4 u: cap pending float4 results at 8 loads
        // (32 VGPRs) so the allocator never spills a2 to scratch.
        bf16x8 a2[16];
#pragma unroll
        for (int u = 0; u < 16; ++u) {
            const float* p = X + ((size_t)(wrow + l5) << 8) + u * 16 + hi * 8;
            float4 x0 = *(const float4*)p;
            float4 x1 = *(const float4*)(p + 4);
            a2[u] = (bf16x8){ (__bf16)x0.x, (__bf16)x0.y, (__bf16)x0.z, (__bf16)x0.w,
                              (__bf16)x1.x, (__bf16)x1.y, (__bf16)x1.z, (__bf16)x1.w };
            if ((u & 3) == 3) __builtin_amdgcn_sched_barrier(0);
        }

        // ---- phase 1: stage WKF (96 rows, 48KB) and compute scores ----
        __syncthreads();                      // prior readers of BUF done
#pragma unroll
        for (int i = 0; i < 12; ++i)
            STAGE_CHUNK(Wkf, 0, i);
        __syncthreads();                      // barrier drain waits staging

        f32x16 acc1[3];
#pragma unroll
        for (int nt = 0; nt < 3; ++nt)
#pragma unroll
            for (int r = 0; r < 16; ++r) acc1[nt][r] = 0.f;
        __builtin_amdgcn_s_setprio(1);
#pragma unroll
        for (int ks = 0; ks < 16; ++ks)
#pragma unroll
            for (int nt = 0; nt < 3; ++nt) {
                int n = nt * 32 + l5;
                bf16x8 b = *(const bf16x8*)&BUF[n * 256 + (((ks * 2 + hi) ^ (n & 7)) << 3)];
                acc1[nt] = MFMA32(a2[ks], b, acc1[nt]);
            }
        __builtin_amdgcn_s_setprio(0);

        // epilogue: combine c-terms, exp, store wgt, accumulate l.
        // sched_barrier per g: keep each g's cmd loads + shuffles local so the
        // transient register peak stays ~20 regs instead of 64+ (anti-spill).
#pragma unroll
        for (int g = 0; g < 4; ++g) {
            bf16x4 wv4;
#pragma unroll
            for (int j = 0; j < 4; ++j) {
                const int r = g * 4 + j;
                const int row32 = j + 8 * g + 4 * hi;
                float4 cm = cmd[wrow + row32];
                float e0, e1, t0[3], t1[3];
#pragma unroll
                for (int nt = 0; nt < 3; ++nt) {
                    e0 = acc1[nt][r];
                    e1 = __shfl_xor(e0, 16);
                    t0[nt] = low ? e0 : e1;
                    t1[nt] = low ? e1 : e0;
                }
                float sc = t0[0] + cm.x * t1[0] + cm.y * t0[1]
                                 + cm.z * t1[1] + cm.w * t0[2];
                float w = __expf(sc);
                wv4[j] = (__bf16)w;
                float ws = w;
                ws += __shfl_xor(ws, 1); ws += __shfl_xor(ws, 2);
                ws += __shfl_xor(ws, 4); ws += __shfl_xor(ws, 8);
                l_i[r] += ws;
            }
            if (low) *(bf16x4*)&WGTs[fl * 128 + (wid << 5) + 8 * g + 4 * hi] = wv4;
            __builtin_amdgcn_sched_barrier(0);
        }

        __syncthreads();                      // phase-1 BUF reads done

        // first V tile of this half -> buf0 (cold once per half; L2-resident)
        {
            const __bf16* base = WV + ((size_t)(h * 16) << 14);
#pragma unroll
            for (int i = 0; i < 8; ++i)
                STAGE_CHUNK(base, 0, i);
        }

        // ---- phase 2: 16 V tiles, dbuf, 1 barrier each ----
        for (int f2 = 0; f2 < 16; ++f2) {
            const int bufsel = (f2 & 1) << 14;
            __syncthreads();                  // drains cur staging; ends prev reads
            if (f2 < 15) {                    // prefetch next tile into other buf
                const __bf16* base = WV + ((size_t)(h * 16 + f2 + 1) << 14);
                const int nsel = bufsel ^ 16384;
#pragma unroll
                for (int i = 0; i < 8; ++i)
                    STAGE_CHUNK(base, nsel, i);
            }
            __builtin_amdgcn_sched_barrier(0);   // pin prefetch-issue before MFMAs
            f32x16 acc2[2];
#pragma unroll
            for (int r = 0; r < 16; ++r) { acc2[0][r] = 0.f; acc2[1][r] = 0.f; }
            __builtin_amdgcn_s_setprio(1);
#pragma unroll
            for (int ks = 0; ks < 16; ++ks)
#pragma unroll
                for (int nt = 0; nt < 2; ++nt) {
                    int n = nt * 32 + l5;
                    bf16x8 b = *(const bf16x8*)&BUF[bufsel + n * 256
                                                    + (((ks * 2 + hi) ^ (n & 7)) << 3)];
                    acc2[nt] = MFMA32(a2[ks], b, acc2[nt]);
                }
            __builtin_amdgcn_s_setprio(0);
#pragma unroll
            for (int g = 0; g < 4; ++g) {
                bf16x4 wv = *(const bf16x4*)&WGTs[f2 * 128 + (wid << 5) + 8 * g + 4 * hi];
#pragma unroll
                for (int j = 0; j < 4; ++j) {
                    float w = (float)wv[j];
                    s_acc[0][g * 4 + j] += w * acc2[0][g * 4 + j];
                    s_acc[1][g * 4 + j] += w * acc2[1][g * 4 + j];
                }
            }
        }
    }
#undef STAGE_CHUNK

    // ---- epilogue: divide by l, store ----
#pragma unroll
    for (int g = 0; g < 4; ++g)
#pragma unroll
        for (int j = 0; j < 4; ++j) {
            const int r = g * 4 + j;
            float inv = 1.0f / l_i[r];
            size_t row = (size_t)(wrow + j + 8 * g + 4 * hi);
            out[(row << 6) + l5]      = s_acc[0][r] * inv;
            out[(row << 6) + 32 + l5] = s_acc[1][r] * inv;
        }
}

// ---------------------------------------------------------------------------
extern "C" void kernel_launch(void* const* d_in, const int* in_sizes, int n_in,
                              void* d_out, int out_size, void* d_ws, size_t ws_size,
                              hipStream_t stream)
{
    (void)in_sizes; (void)n_in; (void)out_size; (void)ws_size;
    const float* feature = (const float*)d_in[0];
    const float* hidden  = (const float*)d_in[1];
    const float* command = (const float*)d_in[2];
    const float* Wq      = (const float*)d_in[3];
    const float* Wkz     = (const float*)d_in[4];
    const float* Wkh     = (const float*)d_in[5];
    const float* Wvz     = (const float*)d_in[6];
    const float* Wvh     = (const float*)d_in[7];
    const float* gammaQ  = (const float*)d_in[8];
    const float* betaQ   = (const float*)d_in[9];
    const float* gammaK  = (const float*)d_in[10];
    const float* betaK   = (const float*)d_in[11];

    char* ws = (char*)d_ws;
    __bf16* WV   = (__bf16*)(ws + WS_WV);
    __bf16* WKF  = (__bf16*)(ws + WS_WKF);
    float*  G    = (float*)(ws + WS_G);
    float*  CS   = (float*)(ws + WS_CS);
    float*  CMDP = (float*)(ws + WS_CMDP);
    float*  Tj   = (float*)(ws + WS_T);
    float*  Uj   = (float*)(ws + WS_U);
    float*  Wq2  = (float*)(ws + WS_WQ2);
    float*  C0   = (float*)(ws + WS_C0);
    float*  outp = (float*)d_out;
    __bf16* Gp   = (__bf16*)d_out;            // 16 MB scratch before final write

    hipMemsetAsync(ws + WS_CS, 0, 0x800, stream);
    setup1<<<416, 512, 0, stream>>>(feature, hidden, (const float4*)command,
                                    Wvz, Wvh, WV, CMDP, CS, Gp);
    gram_reduce<<<512, 256, 0, stream>>>(Gp, G);
    rowstats<<<256, 256, 0, stream>>>(Wkz, Wkh, G, CS, Tj, Uj);
    finalize_kernel<<<1, 64, 0, stream>>>(Wq, gammaQ, betaQ, gammaK, betaK,
                                          CMDP, Tj, Uj, Wq2, C0);
    foldK<<<192, 256, 0, stream>>>(Wkz, Wkh, Wq2, C0, WKF);
    fused_attn<<<512, 256, 0, stream>>>(feature, hidden, (const float4*)command,
                                        WV, WKF, outp);
}

// Round 3
// 328.832 us; speedup vs baseline: 1.1374x; 1.0247x over previous
//
#include <hip/hip_runtime.h>
#include <hip/hip_bf16.h>
#include <math.h>

// ---------------------------------------------------------------------------
// FeatureAttnNet v7 for MI355X (gfx950)
//
// score[b,f] = Y0[b,f] + sum_c cmd[b,c]*Yc[b,f], Y = X @ WKfold^T (BN folded,
// additive BN term cancels in softmax). V GEMM fused with softmax weights.
// v7: fused_attn: full-width LDS swizzle q^(n&31) (was q^(n&7) = 4-way bank
//   conflict on every B read, SQ_LDS_BANK_CONFLICT 9.67M). Conflict-free:
//   32 lanes -> 32 distinct 16B slots per row. Same involution on the
//   pre-swizzled global_load_lds source and the ds_read side (rule 21).
//   WGTs stride 128->132 (breaks 16-way ds_write_b64 conflict).
//   R2's anti-spill fences REVERTED (measured: +26MiB write, +2us — harmful).
// setup1 gram: dbuf LDS (2x20KB) + 2-deep register prefetch, 1 barrier/iter.
// Gram: NO atomics — bf16 partials in d_out (scratch before final write).
// ---------------------------------------------------------------------------

typedef float  f32x4   __attribute__((ext_vector_type(4)));
typedef float  f32x16  __attribute__((ext_vector_type(16)));
typedef __bf16 bf16x4  __attribute__((ext_vector_type(4)));
typedef __bf16 bf16x8  __attribute__((ext_vector_type(8)));

#define MFMA16(A, B, C) __builtin_amdgcn_mfma_f32_16x16x32_bf16((A), (B), (C), 0, 0, 0)
#define MFMA32(A, B, C) __builtin_amdgcn_mfma_f32_32x32x16_bf16((A), (B), (C), 0, 0, 0)

#define EPSV 1e-5f

// ---- workspace layout (bytes) ----
#define WS_WV    0x000000u   // 2048*256 bf16 = 1 MiB  [Wvz;Wvh]
#define WS_WKF   0x100000u   // 2*96*256 bf16 = 96 KiB folded K weights (zero-padded)
#define WS_G     0x120000u   // 2*256*256 f32 = 512 KiB
#define WS_CS    0x1A0000u   // 2*256 f32 colsums (zeroed)
#define WS_CMDP  0x1A0800u   // 32*14 f32 cmd partials
#define WS_T     0x1A1800u   // 2048 f32
#define WS_U     0x1A3800u   // 2048 f32
#define WS_WQ2   0x1A5800u   // 256 f32
#define WS_C0    0x1A5C00u   // 64 f32

// async global->LDS, 16B per lane; LDS dest is wave-uniform base + lane*16.
__device__ __forceinline__ void gl_lds16(const void* g, void* l)
{
    __builtin_amdgcn_global_load_lds(
        (const __attribute__((address_space(1))) unsigned int*)g,
        (__attribute__((address_space(3))) unsigned int*)l, 16, 0, 0);
}

// ---------------------------------------------------------------------------
// setup1: blk<128 -> gram partials (bf16 -> d_out); 128..383 -> prepV;
// 384..415 -> cmd stats.
__global__ __launch_bounds__(512, 2) void setup1(const float* __restrict__ feat,
        const float* __restrict__ hid, const float4* __restrict__ cmd,
        const float* __restrict__ Wvz, const float* __restrict__ Wvh,
        __bf16* __restrict__ WV, float* __restrict__ CMDP, float* __restrict__ CS,
        __bf16* __restrict__ Gp)
{
    __shared__ __bf16 T[2 * 256 * 40];        // 40 KiB double buffer
    __shared__ float sm[8][14];
    const int blk = blockIdx.x;
    const int tid = threadIdx.x;

    if (blk >= 384) {                     // ---- cmd stats: 32 blocks ----
        const int b2 = blk - 384;
        float v[14];
#pragma unroll
        for (int k = 0; k < 14; ++k) v[k] = 0.f;
#pragma unroll
        for (int i = 0; i < 4; ++i) {
            float4 c = cmd[(b2 * 4 + i) * 512 + tid];
            v[0] += c.x;  v[1] += c.y;  v[2] += c.z;  v[3] += c.w;
            v[4] += c.x*c.x; v[5] += c.x*c.y; v[6] += c.x*c.z; v[7] += c.x*c.w;
            v[8] += c.y*c.y; v[9] += c.y*c.z; v[10] += c.y*c.w;
            v[11] += c.z*c.z; v[12] += c.z*c.w; v[13] += c.w*c.w;
        }
#pragma unroll
        for (int k = 0; k < 14; ++k) {
            float s = v[k];
#pragma unroll
            for (int off = 32; off; off >>= 1) s += __shfl_xor(s, off);
            if ((tid & 63) == 0) sm[tid >> 6][k] = s;
        }
        __syncthreads();
        if (tid < 14) {
            float s = 0.f;
#pragma unroll
            for (int w = 0; w < 8; ++w) s += sm[w][tid];
            CMDP[b2 * 14 + tid] = s;
        }
        return;
    }
    if (blk >= 128) {                     // ---- prepV: 256 blocks ----
        int t = (blk - 128) * 512 + tid;
        int e = t * 4;
        const float* src = (e < 262144) ? (Wvz + e) : (Wvh + (e - 262144));
        float4 a = *(const float4*)src;
        bf16x4 vv = { (__bf16)a.x, (__bf16)a.y, (__bf16)a.z, (__bf16)a.w };
        *(bf16x4*)(WV + e) = vv;
        return;
    }

    // ---- gram: 128 blocks = 2 mats x 64 chunks x 1024 rows ----
    // Pipelined: T dbuf, 2-deep reg prefetch, 1 barrier per 32-row step.
    const int mat  = blk >> 6;
    const int chunk = blk & 63;
    const float* X = mat ? hid : feat;
    float* cs = CS + mat * 256;
    const int k0   = chunk * 1024;
    const int wid  = tid >> 6, lane = tid & 63, quad = lane >> 4, l15 = lane & 15;
    const int c    = tid & 255;
    const int t8   = tid >> 8;

    f32x4 acc[2][16];
#pragma unroll
    for (int mt = 0; mt < 2; ++mt)
#pragma unroll
        for (int nt = 0; nt < 16; ++nt) acc[mt][nt] = (f32x4){0.f, 0.f, 0.f, 0.f};

    const float* Xc = X + (size_t)k0 * 256 + c;   // element (k, c) at Xc[k*256]
    float ra[16], rb[16];
    float clsum = 0.f;

#define GRAM_LOAD(R, IT) do { \
        const float* p_ = Xc + (size_t)(IT) * 32 * 256; \
        _Pragma("unroll") \
        for (int i_ = 0; i_ < 16; ++i_) (R)[i_] = p_[(size_t)(t8 + 2 * i_) * 256]; \
    } while (0)
#define GRAM_WRITE(R, BUFO) do { \
        _Pragma("unroll") \
        for (int i_ = 0; i_ < 16; ++i_) { \
            float x_ = (R)[i_]; clsum += x_; \
            T[(BUFO) + c * 40 + t8 + 2 * i_] = (__bf16)x_; } \
    } while (0)
#define GRAM_MFMA(BUFO) do { \
        const __bf16* Tb_ = &T[(BUFO)]; \
        bf16x8 a0_ = *(const bf16x8*)&Tb_[(wid * 32 +      l15) * 40 + quad * 8]; \
        bf16x8 a1_ = *(const bf16x8*)&Tb_[(wid * 32 + 16 + l15) * 40 + quad * 8]; \
        _Pragma("unroll") \
        for (int nt_ = 0; nt_ < 16; ++nt_) { \
            bf16x8 b_ = *(const bf16x8*)&Tb_[(nt_ * 16 + l15) * 40 + quad * 8]; \
            acc[0][nt_] = MFMA16(a0_, b_, acc[0][nt_]); \
            acc[1][nt_] = MFMA16(a1_, b_, acc[1][nt_]); } \
    } while (0)

    GRAM_LOAD(ra, 0);                     // it0
    GRAM_LOAD(rb, 1);                     // it1
    GRAM_WRITE(ra, 0);                    // it0 -> T0
    GRAM_LOAD(ra, 2);                     // it2 (consumed body B of it2=0)
    __syncthreads();

    for (int it2 = 0; it2 < 16; ++it2) {
        // body A: write rb (it 2*it2+1) -> T1; refill rb <- it 2*it2+3; MFMA T0
        GRAM_WRITE(rb, 10240);
        if (it2 < 15) GRAM_LOAD(rb, 2 * it2 + 3);
        GRAM_MFMA(0);
        __syncthreads();
        // body B: write ra (it 2*it2+2) -> T0; refill ra <- it 2*it2+4; MFMA T1
        if (it2 < 15) {
            GRAM_WRITE(ra, 0);
            if (it2 < 14) GRAM_LOAD(ra, 2 * it2 + 4);
        }
        GRAM_MFMA(10240);
        __syncthreads();
    }
#undef GRAM_LOAD
#undef GRAM_WRITE
#undef GRAM_MFMA

    atomicAdd(&cs[c], clsum);             // 512 addrs, 128-way — cheap
    __bf16* outp = Gp + (size_t)blk * 65536;
#pragma unroll
    for (int mt = 0; mt < 2; ++mt)
#pragma unroll
        for (int nt = 0; nt < 16; ++nt)
#pragma unroll
            for (int r = 0; r < 4; ++r) {
                int gi = wid * 32 + mt * 16 + quad * 4 + r;
                int gj = nt * 16 + l15;
                outp[gi * 256 + gj] = (__bf16)acc[mt][nt][r];
            }
}

// ---------------------------------------------------------------------------
__global__ void gram_reduce(const __bf16* __restrict__ Gp, float* __restrict__ G)
{
    int o = blockIdx.x * 256 + threadIdx.x;      // 512 x 256 = 131072
    int mat = o >> 16, e = o & 65535;
    const __bf16* p = Gp + (size_t)mat * 64 * 65536 + e;
    float s = 0.f;
#pragma unroll 8
    for (int c = 0; c < 64; ++c) s += (float)p[(size_t)c * 65536];
    G[o] = s;
}

// ---------------------------------------------------------------------------
__global__ void rowstats(const float* __restrict__ Wkz, const float* __restrict__ Wkh,
        const float* __restrict__ G, const float* __restrict__ CS,
        float* __restrict__ Tout, float* __restrict__ Uout)
{
    const int blk = blockIdx.x;               // 256 blocks
    const int mat = blk >> 7, jg = blk & 127;
    const float* Wsrc = (mat ? Wkh : Wkz) + (size_t)jg * 8 * 256;
    const float* Gm = G + (size_t)mat * 65536;
    const float* cs = CS + mat * 256;
    __shared__ float wlT[256 * 8];
    __shared__ float red[4][16];
    const int tid = threadIdx.x, wid = tid >> 6, lane = tid & 63;
#pragma unroll
    for (int jj = 0; jj < 8; ++jj) wlT[tid * 8 + jj] = Wsrc[jj * 256 + tid];
    __syncthreads();
    float inner[8];
#pragma unroll
    for (int jj = 0; jj < 8; ++jj) inner[jj] = 0.f;
    for (int r = 0; r < 256; ++r) {
        float g = Gm[r * 256 + tid];
        float4 w0 = *(const float4*)&wlT[r * 8];
        float4 w1 = *(const float4*)&wlT[r * 8 + 4];
        inner[0] = fmaf(w0.x, g, inner[0]); inner[1] = fmaf(w0.y, g, inner[1]);
        inner[2] = fmaf(w0.z, g, inner[2]); inner[3] = fmaf(w0.w, g, inner[3]);
        inner[4] = fmaf(w1.x, g, inner[4]); inner[5] = fmaf(w1.y, g, inner[5]);
        inner[6] = fmaf(w1.z, g, inner[6]); inner[7] = fmaf(w1.w, g, inner[7]);
    }
    float cst = cs[tid];
#pragma unroll
    for (int jj = 0; jj < 8; ++jj) {
        float wme = wlT[tid * 8 + jj];
        float p = wme * inner[jj];
        float u = wme * cst;
#pragma unroll
        for (int off = 32; off; off >>= 1) { p += __shfl_xor(p, off); u += __shfl_xor(u, off); }
        if (lane == 0) { red[wid][jj] = p; red[wid][jj + 8] = u; }
    }
    __syncthreads();
    if (tid < 16) {
        float s = red[0][tid] + red[1][tid] + red[2][tid] + red[3][tid];
        int jj = tid & 7;
        int j = mat * 1024 + jg * 8 + jj;
        if (tid < 8) Tout[j] = s; else Uout[j] = s;
    }
}

// ---------------------------------------------------------------------------
__global__ void finalize_kernel(const float* __restrict__ Wq,
        const float* __restrict__ gQ, const float* __restrict__ bQ,
        const float* __restrict__ gK, const float* __restrict__ bK,
        const float* __restrict__ CMDP, const float* __restrict__ T,
        const float* __restrict__ U, float* __restrict__ Wq2, float* __restrict__ C0)
{
    __shared__ float s14[14];
    const int d = threadIdx.x;
    if (d < 14) {
        float s = 0.f;
        for (int b = 0; b < 32; ++b) s += CMDP[b * 14 + d];
        s14[d] = s;
    }
    __syncthreads();
    float s4[4] = { s14[0], s14[1], s14[2], s14[3] };
    float gc[4][4];
    gc[0][0] = s14[4];
    gc[0][1] = gc[1][0] = s14[5];
    gc[0][2] = gc[2][0] = s14[6];
    gc[0][3] = gc[3][0] = s14[7];
    gc[1][1] = s14[8];
    gc[1][2] = gc[2][1] = s14[9];
    gc[1][3] = gc[3][1] = s14[10];
    gc[2][2] = s14[11];
    gc[2][3] = gc[3][2] = s14[12];
    gc[3][3] = s14[13];
    float wq[4];
#pragma unroll
    for (int c = 0; c < 4; ++c) wq[c] = Wq[d * 4 + c];
    const float invB = 1.0f / 65536.0f;
    float mQ = (wq[0]*s4[0] + wq[1]*s4[1] + wq[2]*s4[2] + wq[3]*s4[3]) * invB;
    float eq2 = 0.f;
#pragma unroll
    for (int c = 0; c < 4; ++c)
#pragma unroll
        for (int c2 = 0; c2 < 4; ++c2) eq2 += wq[c] * wq[c2] * gc[c][c2];
    eq2 *= invB;
    float vQ  = eq2 - mQ * mQ;
    float aQ  = gQ[d] / sqrtf(vQ + EPSV);
    float bQv = bQ[d] - mQ * aQ;
    float S2 = 0.f, S1 = 0.f;
#pragma unroll
    for (int f = 0; f < 32; ++f) { S2 += T[f * 64 + d]; S1 += U[f * 64 + d]; }
    const float invBF = 1.0f / (65536.0f * 32.0f);
    float e2 = S2 * invBF, mK = S1 * invBF;
    float vK = e2 - mK * mK;
    float aK = gK[d] / sqrtf(vK + EPSV);
    float c1 = aQ * aK * 0.125f;      // 1/sqrt(64) folded in
    C0[d] = bQv * aK * 0.125f;
#pragma unroll
    for (int c = 0; c < 4; ++c) Wq2[d * 4 + c] = c1 * wq[c];
}

// ---------------------------------------------------------------------------
// WKF[h][r = c*16 + fl][k] = sum_d coef_c[d]*W_h[fl*64+d][k]; rows 80..95 = 0.
__global__ void foldK(const float* __restrict__ Wkz, const float* __restrict__ Wkh,
                      const float* __restrict__ Wq2, const float* __restrict__ C0,
                      __bf16* __restrict__ WKF)
{
    const int blk = blockIdx.x;               // 192
    const int h = blk / 96, rr = blk % 96;
    const int k = threadIdx.x;
    float s = 0.f;
    if (rr < 80) {
        const int c = rr >> 4, fl = rr & 15;
        const float* Wsrc = (h ? Wkh : Wkz) + (size_t)fl * 64 * 256;
        for (int d = 0; d < 64; ++d) {
            float coef = (c == 0) ? C0[d] : Wq2[d * 4 + (c - 1)];
            s = fmaf(coef, Wsrc[d * 256 + k], s);
        }
    }
    WKF[(size_t)(h * 96 + rr) * 256 + k] = (__bf16)s;
}

// ---------------------------------------------------------------------------
// fused_attn v7: 512 blocks x 256 threads; wave = 32 rows; B staged via
// global_load_lds (linear LDS dest, pre-swizzled global src, q^(n&31) full
// swizzle = conflict-free ds_read_b128); dbuf V tiles, 1 barrier per tile;
// X read once; setprio(1) around MFMA cluster.
__global__ __launch_bounds__(256, 2) void fused_attn(
        const float* __restrict__ feat, const float* __restrict__ hid,
        const float4* __restrict__ cmd, const __bf16* __restrict__ WV,
        const __bf16* __restrict__ WKF, float* __restrict__ out)
{
    __shared__ __bf16 BUF[32768];             // 64 KiB (dbuf 2x32KB / p1 48KB)
    __shared__ __bf16 WGTs[16 * 132];         // [f][row], stride 132 (bank pad)
    const int tid  = threadIdx.x;
    const int wid  = tid >> 6, lane = tid & 63;
    const int l5   = lane & 31, hi = lane >> 5;
    const int fl   = l5 & 15;
    const bool low = (l5 < 16);
    const int wrow = (blockIdx.x << 7) + (wid << 5);   // wave's 32 rows

    // Staging chunk i (per wave): rows n = wid*2 + i*8 + hi, 64 lanes x 16B =
    // 1KiB linear LDS at elem (wid*2+i*8)*256. Source slot pre-swizzled:
    // BUF[n*256 + s*8..] = SRC[n*256 + (s^(n&31))*8..]. Read at slot
    // q^(n&31) returns SRC slot q. 32 lanes -> 32 distinct slots: conflict-free.
#define STAGE_CHUNK(SRC, DSTBASE, I) do { \
        int n_ = (wid << 1) + ((I) << 3) + hi; \
        gl_lds16((SRC) + n_ * 256 + ((l5 ^ (n_ & 31)) << 3), \
                 &BUF[(DSTBASE) + (((wid << 1) + ((I) << 3)) << 8)]); \
    } while (0)

    float l_i[16];
    f32x16 s_acc[2];
#pragma unroll
    for (int r = 0; r < 16; ++r) { l_i[r] = 0.f; s_acc[0][r] = 0.f; s_acc[1][r] = 0.f; }

    for (int h = 0; h < 2; ++h) {
        const float* X = h ? hid : feat;
        const __bf16* Wkf = WKF + ((size_t)h * 96 << 8);

        // ---- A fragments (32x32x16): row wrow+l5, k = u*16 + hi*8 + j ----
        bf16x8 a2[16];
#pragma unroll
        for (int u = 0; u < 16; ++u) {
            const float* p = X + ((size_t)(wrow + l5) << 8) + u * 16 + hi * 8;
            float4 x0 = *(const float4*)p;
            float4 x1 = *(const float4*)(p + 4);
            a2[u] = (bf16x8){ (__bf16)x0.x, (__bf16)x0.y, (__bf16)x0.z, (__bf16)x0.w,
                              (__bf16)x1.x, (__bf16)x1.y, (__bf16)x1.z, (__bf16)x1.w };
        }

        // ---- phase 1: stage WKF (96 rows, 48KB) and compute scores ----
        __syncthreads();                      // prior readers of BUF done
#pragma unroll
        for (int i = 0; i < 12; ++i)
            STAGE_CHUNK(Wkf, 0, i);
        __syncthreads();                      // barrier drain waits staging

        f32x16 acc1[3];
#pragma unroll
        for (int nt = 0; nt < 3; ++nt)
#pragma unroll
            for (int r = 0; r < 16; ++r) acc1[nt][r] = 0.f;
        __builtin_amdgcn_s_setprio(1);
#pragma unroll
        for (int ks = 0; ks < 16; ++ks)
#pragma unroll
            for (int nt = 0; nt < 3; ++nt) {
                int n = nt * 32 + l5;
                bf16x8 b = *(const bf16x8*)&BUF[n * 256 + (((ks * 2 + hi) ^ (n & 31)) << 3)];
                acc1[nt] = MFMA32(a2[ks], b, acc1[nt]);
            }
        __builtin_amdgcn_s_setprio(0);

        // epilogue: combine c-terms, exp, store wgt, accumulate l
#pragma unroll
        for (int g = 0; g < 4; ++g) {
            bf16x4 wv4;
#pragma unroll
            for (int j = 0; j < 4; ++j) {
                const int r = g * 4 + j;
                const int row32 = j + 8 * g + 4 * hi;
                float4 cm = cmd[wrow + row32];
                float e0, e1, t0[3], t1[3];
#pragma unroll
                for (int nt = 0; nt < 3; ++nt) {
                    e0 = acc1[nt][r];
                    e1 = __shfl_xor(e0, 16);
                    t0[nt] = low ? e0 : e1;
                    t1[nt] = low ? e1 : e0;
                }
                float sc = t0[0] + cm.x * t1[0] + cm.y * t0[1]
                                 + cm.z * t1[1] + cm.w * t0[2];
                float w = __expf(sc);
                wv4[j] = (__bf16)w;
                float ws = w;
                ws += __shfl_xor(ws, 1); ws += __shfl_xor(ws, 2);
                ws += __shfl_xor(ws, 4); ws += __shfl_xor(ws, 8);
                l_i[r] += ws;
            }
            if (low) *(bf16x4*)&WGTs[fl * 132 + (wid << 5) + 8 * g + 4 * hi] = wv4;
        }

        __syncthreads();                      // phase-1 BUF reads done

        // first V tile of this half -> buf0 (cold once per half; L2-resident)
        {
            const __bf16* base = WV + ((size_t)(h * 16) << 14);
#pragma unroll
            for (int i = 0; i < 8; ++i)
                STAGE_CHUNK(base, 0, i);
        }

        // ---- phase 2: 16 V tiles, dbuf, 1 barrier each ----
        for (int f2 = 0; f2 < 16; ++f2) {
            const int bufsel = (f2 & 1) << 14;
            __syncthreads();                  // drains cur staging; ends prev reads
            if (f2 < 15) {                    // prefetch next tile into other buf
                const __bf16* base = WV + ((size_t)(h * 16 + f2 + 1) << 14);
                const int nsel = bufsel ^ 16384;
#pragma unroll
                for (int i = 0; i < 8; ++i)
                    STAGE_CHUNK(base, nsel, i);
            }
            __builtin_amdgcn_sched_barrier(0);   // pin prefetch-issue before MFMAs
            f32x16 acc2[2];
#pragma unroll
            for (int r = 0; r < 16; ++r) { acc2[0][r] = 0.f; acc2[1][r] = 0.f; }
            __builtin_amdgcn_s_setprio(1);
#pragma unroll
            for (int ks = 0; ks < 16; ++ks)
#pragma unroll
                for (int nt = 0; nt < 2; ++nt) {
                    int n = nt * 32 + l5;
                    bf16x8 b = *(const bf16x8*)&BUF[bufsel + n * 256
                                                    + (((ks * 2 + hi) ^ (n & 31)) << 3)];
                    acc2[nt] = MFMA32(a2[ks], b, acc2[nt]);
                }
            __builtin_amdgcn_s_setprio(0);
#pragma unroll
            for (int g = 0; g < 4; ++g) {
                bf16x4 wv = *(const bf16x4*)&WGTs[f2 * 132 + (wid << 5) + 8 * g + 4 * hi];
#pragma unroll
                for (int j = 0; j < 4; ++j) {
                    float w = (float)wv[j];
                    s_acc[0][g * 4 + j] += w * acc2[0][g * 4 + j];
                    s_acc[1][g * 4 + j] += w * acc2[1][g * 4 + j];
                }
            }
        }
    }
#undef STAGE_CHUNK

    // ---- epilogue: divide by l, store ----
#pragma unroll
    for (int g = 0; g < 4; ++g)
#pragma unroll
        for (int j = 0; j < 4; ++j) {
            const int r = g * 4 + j;
            float inv = 1.0f / l_i[r];
            size_t row = (size_t)(wrow + j + 8 * g + 4 * hi);
            out[(row << 6) + l5]      = s_acc[0][r] * inv;
            out[(row << 6) + 32 + l5] = s_acc[1][r] * inv;
        }
}

// ---------------------------------------------------------------------------
extern "C" void kernel_launch(void* const* d_in, const int* in_sizes, int n_in,
                              void* d_out, int out_size, void* d_ws, size_t ws_size,
                              hipStream_t stream)
{
    (void)in_sizes; (void)n_in; (void)out_size; (void)ws_size;
    const float* feature = (const float*)d_in[0];
    const float* hidden  = (const float*)d_in[1];
    const float* command = (const float*)d_in[2];
    const float* Wq      = (const float*)d_in[3];
    const float* Wkz     = (const float*)d_in[4];
    const float* Wkh     = (const float*)d_in[5];
    const float* Wvz     = (const float*)d_in[6];
    const float* Wvh     = (const float*)d_in[7];
    const float* gammaQ  = (const float*)d_in[8];
    const float* betaQ   = (const float*)d_in[9];
    const float* gammaK  = (const float*)d_in[10];
    const float* betaK   = (const float*)d_in[11];

    char* ws = (char*)d_ws;
    __bf16* WV   = (__bf16*)(ws + WS_WV);
    __bf16* WKF  = (__bf16*)(ws + WS_WKF);
    float*  G    = (float*)(ws + WS_G);
    float*  CS   = (float*)(ws + WS_CS);
    float*  CMDP = (float*)(ws + WS_CMDP);
    float*  Tj   = (float*)(ws + WS_T);
    float*  Uj   = (float*)(ws + WS_U);
    float*  Wq2  = (float*)(ws + WS_WQ2);
    float*  C0   = (float*)(ws + WS_C0);
    float*  outp = (float*)d_out;
    __bf16* Gp   = (__bf16*)d_out;            // 16 MB scratch before final write

    hipMemsetAsync(ws + WS_CS, 0, 0x800, stream);
    setup1<<<416, 512, 0, stream>>>(feature, hidden, (const float4*)command,
                                    Wvz, Wvh, WV, CMDP, CS, Gp);
    gram_reduce<<<512, 256, 0, stream>>>(Gp, G);
    rowstats<<<256, 256, 0, stream>>>(Wkz, Wkh, G, CS, Tj, Uj);
    finalize_kernel<<<1, 64, 0, stream>>>(Wq, gammaQ, betaQ, gammaK, betaK,
                                          CMDP, Tj, Uj, Wq2, C0);
    foldK<<<192, 256, 0, stream>>>(Wkz, Wkh, Wq2, C0, WKF);
    fused_attn<<<512, 256, 0, stream>>>(feature, hidden, (const float4*)command,
                                        WV, WKF, outp);
}